// Round 17
// baseline (768.346 us; speedup 1.0000x reference)
//
#include <hip/hip_runtime.h>
#include <hip/hip_bf16.h>
#include <stdint.h>

// Problem constants: B=4, S=2048, IN=4096, OUT=11008
#define M_DIM 8192   // B*S
#define N_DIM 11008  // OUT
#define K_DIM 4096   // IN
#define NGROUP 32    // K_DIM/128

#define BM 256
#define BN 256
#define BK 64
#define NT (K_DIM / BK)  // 64 K-tiles

typedef __attribute__((ext_vector_type(4))) float f32x4;
typedef __attribute__((ext_vector_type(8))) short short8;
typedef __attribute__((ext_vector_type(8))) __bf16 bf16x8;

static_assert(M_DIM % BM == 0 && N_DIM % BN == 0 && K_DIM % BK == 0, "tiling");

__device__ __forceinline__ unsigned short f2bf(float f) {
  union { float f; unsigned int u; } v; v.f = f;
  unsigned int r = v.u + 0x7FFFu + ((v.u >> 16) & 1u);  // RNE
  return (unsigned short)(r >> 16);
}

// ---------- prepass 1: x fp32 -> bf16 ----------
__global__ __launch_bounds__(256) void cvt_x_kernel(const float* __restrict__ x,
                                                    unsigned short* __restrict__ xb) {
  size_t i = ((size_t)blockIdx.x * 256 + threadIdx.x) * 8;
  float4 a = *(const float4*)(x + i);
  float4 b = *(const float4*)(x + i + 4);
  short8 o;
  o[0] = (short)f2bf(a.x); o[1] = (short)f2bf(a.y);
  o[2] = (short)f2bf(a.z); o[3] = (short)f2bf(a.w);
  o[4] = (short)f2bf(b.x); o[5] = (short)f2bf(b.y);
  o[6] = (short)f2bf(b.z); o[7] = (short)f2bf(b.w);
  *(short8*)(xb + i) = o;
}

// ---------- prepass 2: dequant packed int4 -> bf16 W[N][K] ----------
__global__ __launch_bounds__(256) void dequant_kernel(const int* __restrict__ qw,
                                                      const float* __restrict__ sc,
                                                      const float* __restrict__ zp,
                                                      unsigned short* __restrict__ W) {
  size_t chunk = (size_t)blockIdx.x * 256 + threadIdx.x;  // 4 packed int32 = 8 weights
  int row = (int)(chunk >> 9);
  int c4  = (int)(chunk & 511);
  int g   = c4 >> 4;
  float s = sc[row * NGROUP + g];
  float z = zp[row * NGROUP + g];
  int4 q = *(const int4*)(qw + (size_t)row * 2048 + c4 * 4);
  int qq[4] = {q.x, q.y, q.z, q.w};
  short8 o;
#pragma unroll
  for (int t = 0; t < 4; ++t) {
    o[2 * t]     = (short)f2bf(((float)(qq[t] & 15)        - z) * s);
    o[2 * t + 1] = (short)f2bf(((float)((qq[t] >> 4) & 15) - z) * s);
  }
  *(short8*)(W + (size_t)row * K_DIM + (size_t)c4 * 8) = o;
}

// ---------- 256x256 GEMM, reg-pipelined frags + sched_group_barrier interleave ----------
__device__ __forceinline__ void gload_lds16(const void* g, void* l) {
  __builtin_amdgcn_global_load_lds((__attribute__((address_space(1))) void*)g,
                                   (__attribute__((address_space(3))) void*)l,
                                   16, 0, 0);
}

// Stage one k-half panel [256 rows][32 cols] (16KB), 2 gload_lds per thread.
__device__ __forceinline__ void stage2(const unsigned short* s0,
                                       const unsigned short* s1,
                                       unsigned short* panel, int wave, int koff) {
  gload_lds16(s0 + koff, panel + wave * 512);
  gload_lds16(s1 + koff, panel + 4096 + wave * 512);
}

#define VMC(N) asm volatile("s_waitcnt vmcnt(" #N ")" ::: "memory")
#define PUB(N) { VMC(N); __builtin_amdgcn_s_barrier(); }   // publish point

#define SGB __builtin_amdgcn_sched_group_barrier
// masks: MFMA=0x8, DS_READ=0x100

// Fragment reads (pure ds_read; results consumed one phase later).
#define RD_AV(DST, P, MH)                                                    \
  _Pragma("unroll") for (int m_ = 0; m_ < 4; ++m_)                           \
    DST[m_] = *(const bf16x8*)&(P)[abase + ((MH)*4 + m_) * 512];
#define RD_BV(DST, P)                                                        \
  _Pragma("unroll") for (int n_ = 0; n_ < 4; ++n_)                           \
    DST[n_] = *(const bf16x8*)&(P)[bbase + n_ * 512];

// MFMA cluster on registers loaded one phase earlier.
#define MFMA_BLK(MH, AV, BV)                                                 \
  {                                                                          \
    __builtin_amdgcn_s_setprio(1);                                           \
    _Pragma("unroll") for (int m_ = 0; m_ < 4; ++m_)                         \
      _Pragma("unroll") for (int n_ = 0; n_ < 4; ++n_)                       \
        acc[(MH)*4 + m_][n_] = __builtin_amdgcn_mfma_f32_16x16x32_bf16(      \
            AV[m_], BV[n_], acc[(MH)*4 + m_][n_], 0, 0, 0);                  \
    __builtin_amdgcn_s_setprio(0);                                           \
  }

// Interleave templates: weave DS_READs between MFMAs within the region.
#define WEAVE(NDS, MPRE, MPER, MPOST)                                        \
  {                                                                          \
    SGB(0x8, MPRE, 0);                                                       \
    _Pragma("unroll") for (int w_ = 0; w_ < NDS; ++w_) {                     \
      SGB(0x100, 1, 0);                                                      \
      SGB(0x8, MPER, 0);                                                     \
    }                                                                        \
    SGB(0x8, MPOST, 0);                                                      \
  }

__global__ __launch_bounds__(512, 2) void gemm_8phase_kernel(const unsigned short* __restrict__ A,
                                                             const unsigned short* __restrict__ B,
                                                             float* __restrict__ C) {
  extern __shared__ unsigned short lds[];
  unsigned short* As = lds;            // [2 buf][2 kh][256*32]  = 64KB
  unsigned short* Bs = lds + 32768;    // same                   = 64KB

  const int tid  = threadIdx.x;
  const int wave = tid >> 6;
  const int lane = tid & 63;
  const int wm = wave >> 2;   // 0..1 -> 128-row slab
  const int wn = wave & 3;    // 0..3 -> 64-col slab
  const int fr = lane & 15;
  const int cp = (lane >> 4) ^ ((fr >> 1) & 3);  // swizzled physical 16B-block (0-conflict)

  // XCD-chunked block swizzle (1376 = 8*172, bijective), bm-major mapping
  const int wg  = blockIdx.x;
  const int sz_ = (wg & 7) * 172 + (wg >> 3);
  const int bm = sz_ / 43;
  const int bn = sz_ % 43;
  const size_t row0 = (size_t)bm * BM;
  const size_t col0 = (size_t)bn * BN;

  const unsigned short* Ab = A + row0 * K_DIM;
  const unsigned short* Bb = B + col0 * K_DIM;

  // precomputed per-lane staging sources (swizzle baked into global col, rule #21)
  const int cl = (tid & 3) ^ ((tid >> 3) & 3);
  const int r0 = tid >> 2;
  const unsigned short* asrc0 = Ab + (size_t)r0 * K_DIM + cl * 8;
  const unsigned short* asrc1 = Ab + (size_t)(r0 + 128) * K_DIM + cl * 8;
  const unsigned short* bsrc0 = Bb + (size_t)r0 * K_DIM + cl * 8;
  const unsigned short* bsrc1 = Bb + (size_t)(r0 + 128) * K_DIM + cl * 8;

  // fragment LDS element offsets (panel-local); frag mi at abase + mi*512
  const int abase = (wm * 128 + fr) * 32 + cp * 8;
  const int bbase = (wn * 64 + fr) * 32 + cp * 8;

  f32x4 acc[8][4];
#pragma unroll
  for (int i = 0; i < 8; ++i)
#pragma unroll
    for (int j = 0; j < 4; ++j) acc[i][j] = (f32x4){0.f, 0.f, 0.f, 0.f};

  // ping-pong fragment register sets
  bf16x8 av0[4], av1[4], bv0[4], bv1[4];

  // ---- prologue: stage tile 0 fully; pre-read P1's fragments ----
  stage2(asrc0, asrc1, As + 0 * 8192, wave, 0);
  stage2(bsrc0, bsrc1, Bs + 0 * 8192, wave, 0);
  stage2(asrc0, asrc1, As + 1 * 8192, wave, 32);
  stage2(bsrc0, bsrc1, Bs + 1 * 8192, wave, 32);
  VMC(4);                       // A0,B0 landed; A1,B1 may be in flight
  __builtin_amdgcn_s_barrier();
  RD_AV(av0, As + 0 * 8192, 0);
  RD_BV(bv0, Bs + 0 * 8192);

  // ---- main loop: 4 phases/K-tile; each phase pre-reads the NEXT phase's frags;
  //      sched_group_barrier weaves the DS_READs between the MFMAs per region ----
  for (int T = 0; T < NT - 1; ++T) {
    const int buf = T & 1, nb = buf ^ 1;
    unsigned short* A0 = As + (buf * 2 + 0) * 8192;
    unsigned short* A1 = As + (buf * 2 + 1) * 8192;
    unsigned short* B0 = Bs + (buf * 2 + 0) * 8192;
    unsigned short* B1 = Bs + (buf * 2 + 1) * 8192;
    unsigned short* nA0 = As + (nb * 2 + 0) * 8192;
    unsigned short* nA1 = As + (nb * 2 + 1) * 8192;
    unsigned short* nB0 = Bs + (nb * 2 + 0) * 8192;
    unsigned short* nB1 = Bs + (nb * 2 + 1) * 8192;
    const int k0 = (T + 1) * 64;      // prefetch col offset (elems)

    // P1 (region A): MFMA(k0,mh0); pre-read av1<-A0.mh1 (4 DS); stage nA0;
    //     PUBLISH kh1 (VMC(2): retires A1,B1; leaves nA0 in flight)
    RD_AV(av1, A0, 1);
    stage2(asrc0, asrc1, nA0, wave, k0);
    MFMA_BLK(0, av0, bv0);
    WEAVE(4, 2, 3, 2);                 // 4 DS woven into 16 MFMA
    PUB(2);
    // P2+P3 (region B): 32 MFMA, 12 DS
    RD_AV(av0, A1, 0);
    RD_BV(bv1, B1);
    stage2(bsrc0, bsrc1, nB0, wave, k0);
    MFMA_BLK(1, av1, bv0);
    RD_AV(av1, A1, 1);
    stage2(asrc0, asrc1, nA1, wave, k0 + 32);
    MFMA_BLK(0, av0, bv1);
    WEAVE(12, 2, 2, 6);                // 12 DS woven into 32 MFMA
    PUB(2);
    // P4 (region C): MFMA(k1,mh1); pre-read next tile P1 frags (8 DS); stage nB1
    RD_AV(av0, nA0, 0);
    RD_BV(bv0, nB0);
    stage2(bsrc0, bsrc1, nB1, wave, k0 + 32);
    MFMA_BLK(1, av1, bv1);
    WEAVE(8, 2, 1, 6);                 // 8 DS woven into 16 MFMA
  }
  // ---- last tile: no staging; drain kh1 then finish ----
  {
    const int buf = (NT - 1) & 1;
    unsigned short* A0 = As + (buf * 2 + 0) * 8192;
    unsigned short* A1 = As + (buf * 2 + 1) * 8192;
    unsigned short* B1 = Bs + (buf * 2 + 1) * 8192;
    // P1
    RD_AV(av1, A0, 1);
    MFMA_BLK(0, av0, bv0);
    PUB(0);                      // retires nA1,nB1 -> A1,B1 readable
    // P2
    RD_AV(av0, A1, 0);
    RD_BV(bv1, B1);
    MFMA_BLK(1, av1, bv0);
    // P3
    RD_AV(av1, A1, 1);
    MFMA_BLK(0, av0, bv1);
    // P4
    MFMA_BLK(1, av1, bv1);
  }

  // ---- epilogue: C/D layout col = lane&15, row = (lane>>4)*4 + v ----
  const int orow = (lane >> 4) * 4;
#pragma unroll
  for (int mi = 0; mi < 8; ++mi) {
#pragma unroll
    for (int n = 0; n < 4; ++n) {
      const size_t r = row0 + wm * 128 + mi * 16 + orow;
      const size_t c = col0 + wn * 64 + n * 16 + fr;
#pragma unroll
      for (int v = 0; v < 4; ++v)
        C[(r + v) * N_DIM + c] = acc[mi][n][v];
    }
  }
}

// ---------- fallback (only if d_ws too small): naive fused ----------
__global__ __launch_bounds__(256) void fallback_kernel(const float* __restrict__ x,
                                                       const int* __restrict__ qw,
                                                       const float* __restrict__ sc,
                                                       const float* __restrict__ zp,
                                                       float* __restrict__ out) {
  __shared__ float xs[K_DIM];
  const int m = blockIdx.y;
  const int n = blockIdx.x * 256 + threadIdx.x;
  for (int i = threadIdx.x; i < K_DIM; i += 256) xs[i] = x[(size_t)m * K_DIM + i];
  __syncthreads();
  float acc = 0.f;
  const int* wrow = qw + (size_t)n * (K_DIM / 2);
  for (int g = 0; g < NGROUP; ++g) {
    float s = sc[n * NGROUP + g];
    float z = zp[n * NGROUP + g];
    float partial = 0.f;
    for (int p = 0; p < 64; ++p) {
      int q = wrow[g * 64 + p];
      partial += xs[g * 128 + 2 * p]     * ((float)(q & 15) - z);
      partial += xs[g * 128 + 2 * p + 1] * ((float)((q >> 4) & 15) - z);
    }
    acc = fmaf(partial, s, acc);
  }
  out[(size_t)m * N_DIM + n] = acc;
}

extern "C" void kernel_launch(void* const* d_in, const int* in_sizes, int n_in,
                              void* d_out, int out_size, void* d_ws, size_t ws_size,
                              hipStream_t stream) {
  const float* x  = (const float*)d_in[0];
  const int*   qw = (const int*)d_in[1];
  const float* sc = (const float*)d_in[2];
  const float* zp = (const float*)d_in[3];
  float* out = (float*)d_out;

  const size_t xb_bytes = (size_t)M_DIM * K_DIM * 2;
  const size_t wb_bytes = (size_t)N_DIM * K_DIM * 2;

  if (ws_size >= xb_bytes + wb_bytes) {
    unsigned short* xb = (unsigned short*)d_ws;
    unsigned short* wb = (unsigned short*)((char*)d_ws + xb_bytes);
    cvt_x_kernel<<<dim3((unsigned)((size_t)M_DIM * K_DIM / (256 * 8))), 256, 0, stream>>>(x, xb);
    dequant_kernel<<<dim3((unsigned)((size_t)N_DIM * (K_DIM / 2) / 4 / 256)), 256, 0, stream>>>(qw, sc, zp, wb);
    dim3 grid((M_DIM / BM) * (N_DIM / BN));  // 32*43 = 1376
    gemm_8phase_kernel<<<grid, dim3(512), 131072, stream>>>(xb, wb, out);
  } else {
    dim3 grid(N_DIM / 256, M_DIM);
    fallback_kernel<<<grid, 256, 0, stream>>>(x, qw, sc, zp, out);
  }
}

// Round 18
// 460.666 us; speedup vs baseline: 1.6679x; 1.6679x over previous
//
#include <hip/hip_runtime.h>
#include <hip/hip_bf16.h>
#include <stdint.h>

// Problem constants: B=4, S=2048, IN=4096, OUT=11008
#define M_DIM 8192   // B*S
#define N_DIM 11008  // OUT
#define K_DIM 4096   // IN
#define NGROUP 32    // K_DIM/128

#define BM 256
#define BN 256
#define BK 128
#define NT (K_DIM / BK)  // 32 K-tiles

typedef __attribute__((ext_vector_type(4))) int i32x4;
typedef __attribute__((ext_vector_type(4))) float f32x4;

static_assert(M_DIM % BM == 0 && N_DIM % BN == 0 && K_DIM % BK == 0, "tiling");

// ---------- prepass 1: x fp32 -> i8 (per-row scale) ----------
__global__ __launch_bounds__(256) void quant_x_kernel(const float* __restrict__ x,
                                                      int8_t* __restrict__ xq,
                                                      float* __restrict__ sx) {
  const int m = blockIdx.x;
  const int tid = threadIdx.x;
  __shared__ float red[4];
  __shared__ float sfin;
  const float* xr = x + (size_t)m * K_DIM;
  float4 v[4];
  float mx = 0.f;
#pragma unroll
  for (int i = 0; i < 4; ++i) {
    v[i] = *(const float4*)(xr + tid * 16 + i * 4);
    mx = fmaxf(mx, fmaxf(fmaxf(fabsf(v[i].x), fabsf(v[i].y)),
                         fmaxf(fabsf(v[i].z), fabsf(v[i].w))));
  }
#pragma unroll
  for (int off = 32; off; off >>= 1) mx = fmaxf(mx, __shfl_xor(mx, off));
  if ((tid & 63) == 0) red[tid >> 6] = mx;
  __syncthreads();
  if (tid == 0) {
    float t = fmaxf(fmaxf(red[0], red[1]), fmaxf(red[2], red[3]));
    t = fmaxf(t, 1e-20f);
    sfin = t;
    sx[m] = t * (1.0f / 127.0f);
  }
  __syncthreads();
  const float inv = 127.0f / sfin;
  int o[4];
#pragma unroll
  for (int i = 0; i < 4; ++i) {
    int q0 = (int)rintf(v[i].x * inv), q1 = (int)rintf(v[i].y * inv);
    int q2 = (int)rintf(v[i].z * inv), q3 = (int)rintf(v[i].w * inv);
    o[i] = (q0 & 0xff) | ((q1 & 0xff) << 8) | ((q2 & 0xff) << 16) | (q3 << 24);
  }
  *(int4*)(xq + (size_t)m * K_DIM + tid * 16) = make_int4(o[0], o[1], o[2], o[3]);
}

// ---------- prepass 2: packed int4 W -> i8 (per-output-row scale) ----------
__global__ __launch_bounds__(256) void quant_w_kernel(const int* __restrict__ qw,
                                                      const float* __restrict__ sc,
                                                      const float* __restrict__ zp,
                                                      int8_t* __restrict__ wq,
                                                      float* __restrict__ swc) {
  const int o = blockIdx.x * 4 + (threadIdx.x >> 6);
  const int lane = threadIdx.x & 63;
  const int* row = qw + (size_t)o * 2048;
  const float* srow = sc + o * NGROUP;
  const float* zrow = zp + o * NGROUP;
  // pass 1: max |(q - z) * s| over the row (int i covers group g = i exactly)
  float mx = 0.f;
#pragma unroll 4
  for (int i = 0; i < 32; ++i) {
    int q = row[i * 64 + lane];
    float s = srow[i], z = zrow[i];
    float lo = ((float)(q & 15) - z) * s;
    float hi = ((float)((q >> 4) & 15) - z) * s;
    mx = fmaxf(mx, fmaxf(fabsf(lo), fabsf(hi)));
  }
#pragma unroll
  for (int off = 32; off; off >>= 1) mx = fmaxf(mx, __shfl_xor(mx, off));
  mx = fmaxf(mx, 1e-20f);
  if (lane == 0) swc[o] = mx * (1.0f / 127.0f);
  const float inv = 127.0f / mx;
  short* out = (short*)(wq + (size_t)o * K_DIM);
#pragma unroll 4
  for (int i = 0; i < 32; ++i) {
    int q = row[i * 64 + lane];
    float s = srow[i], z = zrow[i];
    int rlo = (int)rintf(((float)(q & 15) - z) * s * inv);
    int rhi = (int)rintf(((float)((q >> 4) & 15) - z) * s * inv);
    out[i * 64 + lane] = (short)((rlo & 0xff) | (rhi << 8));
  }
}

// ---------- 256x256 i8 GEMM, R9 schedule, BK=128 ----------
__device__ __forceinline__ void gload_lds16(const void* g, void* l) {
  __builtin_amdgcn_global_load_lds((__attribute__((address_space(1))) void*)g,
                                   (__attribute__((address_space(3))) void*)l,
                                   16, 0, 0);
}

// Stage one k-half panel [256 rows][64 i8] (16KB), 2 gload_lds per thread.
__device__ __forceinline__ void stage2(const int8_t* s0, const int8_t* s1,
                                       int8_t* panel, int wave, int koff) {
  gload_lds16(s0 + koff, panel + wave * 1024);
  gload_lds16(s1 + koff, panel + 8192 + wave * 1024);
}

#define VMC(N) asm volatile("s_waitcnt vmcnt(" #N ")" ::: "memory")
#define PUB(N) { VMC(N); __builtin_amdgcn_s_barrier(); }

// Fragment reads (i8: 16B = 16 elems along K per lane).
#define RD_AV(DST, P, MH)                                                    \
  _Pragma("unroll") for (int m_ = 0; m_ < 4; ++m_)                           \
    DST[m_] = *(const i32x4*)((P) + abase + ((MH)*4 + m_) * 1024);
#define RD_BV(DST, P)                                                        \
  _Pragma("unroll") for (int n_ = 0; n_ < 4; ++n_)                           \
    DST[n_] = *(const i32x4*)((P) + bbase + n_ * 1024);

#define MFMA_BLK(MH, AV, BV)                                                 \
  {                                                                          \
    __builtin_amdgcn_s_setprio(1);                                           \
    _Pragma("unroll") for (int m_ = 0; m_ < 4; ++m_)                         \
      _Pragma("unroll") for (int n_ = 0; n_ < 4; ++n_)                       \
        acc[(MH)*4 + m_][n_] = __builtin_amdgcn_mfma_i32_16x16x64_i8(        \
            AV[m_], BV[n_], acc[(MH)*4 + m_][n_], 0, 0, 0);                  \
    __builtin_amdgcn_s_setprio(0);                                           \
  }

__global__ __launch_bounds__(512, 2) void gemm_i8_kernel(const int8_t* __restrict__ A,
                                                         const int8_t* __restrict__ B,
                                                         const float* __restrict__ sx,
                                                         const float* __restrict__ swc,
                                                         float* __restrict__ C) {
  extern __shared__ int8_t lds[];
  int8_t* As = lds;            // [2 buf][2 kh][256*64]  = 64KB
  int8_t* Bs = lds + 65536;    // same                   = 64KB

  const int tid  = threadIdx.x;
  const int wave = tid >> 6;
  const int lane = tid & 63;
  const int wm = wave >> 2;   // 0..1 -> 128-row slab
  const int wn = wave & 3;    // 0..3 -> 64-col slab
  const int fr = lane & 15;
  const int cp = (lane >> 4) ^ ((fr >> 1) & 3);  // swizzled physical 16B-block

  // XCD-chunked block swizzle (1376 = 8*172, bijective), bm-major mapping
  const int wg  = blockIdx.x;
  const int sz_ = (wg & 7) * 172 + (wg >> 3);
  const int bm = sz_ / 43;
  const int bn = sz_ % 43;
  const size_t row0 = (size_t)bm * BM;
  const size_t col0 = (size_t)bn * BN;

  const int8_t* Ab = A + row0 * K_DIM;
  const int8_t* Bb = B + col0 * K_DIM;

  // per-lane staging sources (swizzle baked into global col, rule #21)
  const int cl = (tid & 3) ^ ((tid >> 3) & 3);
  const int r0 = tid >> 2;
  const int8_t* asrc0 = Ab + (size_t)r0 * K_DIM + cl * 16;
  const int8_t* asrc1 = Ab + (size_t)(r0 + 128) * K_DIM + cl * 16;
  const int8_t* bsrc0 = Bb + (size_t)r0 * K_DIM + cl * 16;
  const int8_t* bsrc1 = Bb + (size_t)(r0 + 128) * K_DIM + cl * 16;

  // fragment LDS byte offsets (panel-local); frag mf at abase + mf*1024
  const int abase = (wm * 128 + fr) * 64 + cp * 16;
  const int bbase = (wn * 64 + fr) * 64 + cp * 16;

  i32x4 acc[8][4];
#pragma unroll
  for (int i = 0; i < 8; ++i)
#pragma unroll
    for (int j = 0; j < 4; ++j) acc[i][j] = (i32x4){0, 0, 0, 0};

  i32x4 av0[4], av1[4], bv0[4], bv1[4];

  // ---- prologue: stage tile 0 fully; pre-read P1's fragments ----
  stage2(asrc0, asrc1, As + 0 * 16384, wave, 0);
  stage2(bsrc0, bsrc1, Bs + 0 * 16384, wave, 0);
  stage2(asrc0, asrc1, As + 1 * 16384, wave, 64);
  stage2(bsrc0, bsrc1, Bs + 1 * 16384, wave, 64);
  VMC(4);                       // A0,B0 landed; A1,B1 may be in flight
  __builtin_amdgcn_s_barrier();
  RD_AV(av0, As + 0 * 16384, 0);
  RD_BV(bv0, Bs + 0 * 16384);

  // ---- main loop: R9 schedule, 4 phases/K-tile, publishes at P1/P3 ----
  for (int T = 0; T < NT - 1; ++T) {
    const int buf = T & 1, nb = buf ^ 1;
    int8_t* A0 = As + (buf * 2 + 0) * 16384;
    int8_t* A1 = As + (buf * 2 + 1) * 16384;
    int8_t* B1 = Bs + (buf * 2 + 1) * 16384;
    int8_t* nA0 = As + (nb * 2 + 0) * 16384;
    int8_t* nA1 = As + (nb * 2 + 1) * 16384;
    int8_t* nB0 = Bs + (nb * 2 + 0) * 16384;
    int8_t* nB1 = Bs + (nb * 2 + 1) * 16384;
    const int k0 = (T + 1) * 128;     // prefetch col offset (i8 elems)

    // P1: MFMA(kh0,mh0); pre-read av1<-A0.mh1; stage nA0; PUBLISH kh1
    RD_AV(av1, A0, 1);
    stage2(asrc0, asrc1, nA0, wave, k0);
    MFMA_BLK(0, av0, bv0);
    PUB(2);
    // P2: MFMA(kh0,mh1); pre-read av0<-A1.mh0, bv1<-B1; stage nB0
    RD_AV(av0, A1, 0);
    RD_BV(bv1, B1);
    stage2(bsrc0, bsrc1, nB0, wave, k0);
    MFMA_BLK(1, av1, bv0);
    // P3: MFMA(kh1,mh0); pre-read av1<-A1.mh1; stage nA1; PUBLISH next kh0
    RD_AV(av1, A1, 1);
    stage2(asrc0, asrc1, nA1, wave, k0 + 64);
    MFMA_BLK(0, av0, bv1);
    PUB(2);
    // P4: MFMA(kh1,mh1); pre-read next P1 frags from nA0,nB0; stage nB1
    RD_AV(av0, nA0, 0);
    RD_BV(bv0, nB0);
    stage2(bsrc0, bsrc1, nB1, wave, k0 + 64);
    MFMA_BLK(1, av1, bv1);
  }
  // ---- last tile: no staging; drain remaining at P1-end ----
  {
    const int buf = (NT - 1) & 1;
    int8_t* A0 = As + (buf * 2 + 0) * 16384;
    int8_t* A1 = As + (buf * 2 + 1) * 16384;
    int8_t* B1 = Bs + (buf * 2 + 1) * 16384;
    RD_AV(av1, A0, 1);
    MFMA_BLK(0, av0, bv0);
    PUB(0);                      // retires nA1,nB1 -> A1,B1 readable
    RD_AV(av0, A1, 0);
    RD_BV(bv1, B1);
    MFMA_BLK(1, av1, bv0);
    RD_AV(av1, A1, 1);
    MFMA_BLK(0, av0, bv1);
    MFMA_BLK(1, av1, bv1);
  }

  // ---- epilogue: out = sx[row] * swc[col] * (f32)acc ----
  const int orow = (lane >> 4) * 4;
#pragma unroll
  for (int mi = 0; mi < 8; ++mi) {
    const size_t r = row0 + wm * 128 + mi * 16 + orow;
    const f32x4 sx4 = *(const f32x4*)(sx + r);
#pragma unroll
    for (int n = 0; n < 4; ++n) {
      const size_t c = col0 + wn * 64 + n * 16 + fr;
      const float sw = swc[c];
#pragma unroll
      for (int v = 0; v < 4; ++v)
        C[(r + v) * N_DIM + c] = (float)acc[mi][n][v] * sx4[v] * sw;
    }
  }
}

// ---------- fallback (only if d_ws too small): naive fused ----------
__global__ __launch_bounds__(256) void fallback_kernel(const float* __restrict__ x,
                                                       const int* __restrict__ qw,
                                                       const float* __restrict__ sc,
                                                       const float* __restrict__ zp,
                                                       float* __restrict__ out) {
  __shared__ float xs[K_DIM];
  const int m = blockIdx.y;
  const int n = blockIdx.x * 256 + threadIdx.x;
  for (int i = threadIdx.x; i < K_DIM; i += 256) xs[i] = x[(size_t)m * K_DIM + i];
  __syncthreads();
  float acc = 0.f;
  const int* wrow = qw + (size_t)n * (K_DIM / 2);
  for (int g = 0; g < NGROUP; ++g) {
    float s = sc[n * NGROUP + g];
    float z = zp[n * NGROUP + g];
    float partial = 0.f;
    for (int p = 0; p < 64; ++p) {
      int q = wrow[g * 64 + p];
      partial += xs[g * 128 + 2 * p]     * ((float)(q & 15) - z);
      partial += xs[g * 128 + 2 * p + 1] * ((float)((q >> 4) & 15) - z);
    }
    acc = fmaf(partial, s, acc);
  }
  out[(size_t)m * N_DIM + n] = acc;
}

extern "C" void kernel_launch(void* const* d_in, const int* in_sizes, int n_in,
                              void* d_out, int out_size, void* d_ws, size_t ws_size,
                              hipStream_t stream) {
  const float* x  = (const float*)d_in[0];
  const int*   qw = (const int*)d_in[1];
  const float* sc = (const float*)d_in[2];
  const float* zp = (const float*)d_in[3];
  float* out = (float*)d_out;

  const size_t xq_bytes = (size_t)M_DIM * K_DIM;        // 33,554,432
  const size_t wq_bytes = (size_t)N_DIM * K_DIM;        // 45,088,768
  const size_t sx_bytes = (size_t)M_DIM * 4;
  const size_t sw_bytes = (size_t)N_DIM * 4;

  if (ws_size >= xq_bytes + wq_bytes + sx_bytes + sw_bytes) {
    int8_t* xq = (int8_t*)d_ws;
    int8_t* wq = (int8_t*)d_ws + xq_bytes;
    float* sx  = (float*)((char*)d_ws + xq_bytes + wq_bytes);
    float* swc = (float*)((char*)d_ws + xq_bytes + wq_bytes + sx_bytes);
    quant_x_kernel<<<dim3(M_DIM), 256, 0, stream>>>(x, xq, sx);
    quant_w_kernel<<<dim3(N_DIM / 4), 256, 0, stream>>>(qw, sc, zp, wq, swc);
    dim3 grid((M_DIM / BM) * (N_DIM / BN));  // 32*43 = 1376
    gemm_i8_kernel<<<grid, dim3(512), 131072, stream>>>(xq, wq, sx, swc, out);
  } else {
    dim3 grid(N_DIM / 256, M_DIM);
    fallback_kernel<<<grid, 256, 0, stream>>>(x, qw, sc, zp, out);
  }
}

// Round 19
// 443.853 us; speedup vs baseline: 1.7311x; 1.0379x over previous
//
#include <hip/hip_runtime.h>
#include <hip/hip_bf16.h>
#include <stdint.h>

// Problem constants: B=4, S=2048, IN=4096, OUT=11008
#define M_DIM 8192   // B*S
#define N_DIM 11008  // OUT
#define K_DIM 4096   // IN
#define NGROUP 32    // K_DIM/128

#define BM 256
#define BN 256
#define BK 128
#define NT (K_DIM / BK)  // 32 K-tiles

typedef __attribute__((ext_vector_type(4))) int i32x4;
typedef __attribute__((ext_vector_type(4))) float f32x4;

static_assert(M_DIM % BM == 0 && N_DIM % BN == 0 && K_DIM % BK == 0, "tiling");

// ---------- fused prepass: blocks [0,8192) quantize x rows; [8192,10944) quantize W rows ----------
__global__ __launch_bounds__(256) void quant_fused_kernel(const float* __restrict__ x,
                                                          int8_t* __restrict__ xq,
                                                          float* __restrict__ sx,
                                                          const int* __restrict__ qw,
                                                          const float* __restrict__ sc,
                                                          const float* __restrict__ zp,
                                                          int8_t* __restrict__ wq,
                                                          float* __restrict__ swc) {
  __shared__ float red[4];
  __shared__ float sfin;
  const int tid = threadIdx.x;

  if (blockIdx.x < M_DIM) {
    // ---- x row -> i8, per-row scale ----
    const int m = blockIdx.x;
    const float* xr = x + (size_t)m * K_DIM;
    float4 v[4];
    float mx = 0.f;
#pragma unroll
    for (int i = 0; i < 4; ++i) {
      v[i] = *(const float4*)(xr + tid * 16 + i * 4);
      mx = fmaxf(mx, fmaxf(fmaxf(fabsf(v[i].x), fabsf(v[i].y)),
                           fmaxf(fabsf(v[i].z), fabsf(v[i].w))));
    }
#pragma unroll
    for (int off = 32; off; off >>= 1) mx = fmaxf(mx, __shfl_xor(mx, off));
    if ((tid & 63) == 0) red[tid >> 6] = mx;
    __syncthreads();
    if (tid == 0) {
      float t = fmaxf(fmaxf(red[0], red[1]), fmaxf(red[2], red[3]));
      t = fmaxf(t, 1e-20f);
      sfin = t;
      sx[m] = t * (1.0f / 127.0f);
    }
    __syncthreads();
    const float inv = 127.0f / sfin;
    int o[4];
#pragma unroll
    for (int i = 0; i < 4; ++i) {
      int q0 = (int)rintf(v[i].x * inv), q1 = (int)rintf(v[i].y * inv);
      int q2 = (int)rintf(v[i].z * inv), q3 = (int)rintf(v[i].w * inv);
      o[i] = (q0 & 0xff) | ((q1 & 0xff) << 8) | ((q2 & 0xff) << 16) | (q3 << 24);
    }
    *(int4*)(xq + (size_t)m * K_DIM + tid * 16) = make_int4(o[0], o[1], o[2], o[3]);
  } else {
    // ---- W row -> i8, per-output-row scale; SINGLE global read (row held in regs) ----
    const int o = (blockIdx.x - M_DIM) * 4 + (tid >> 6);
    const int lane = tid & 63;
    const int* row = qw + (size_t)o * 2048;
    const float* srow = sc + o * NGROUP;
    const float* zrow = zp + o * NGROUP;
    int q[32];
    float mx = 0.f;
#pragma unroll
    for (int i = 0; i < 32; ++i) {
      q[i] = row[i * 64 + lane];
      float s = srow[i], z = zrow[i];
      float lo = ((float)(q[i] & 15) - z) * s;
      float hi = ((float)((q[i] >> 4) & 15) - z) * s;
      mx = fmaxf(mx, fmaxf(fabsf(lo), fabsf(hi)));
    }
#pragma unroll
    for (int off = 32; off; off >>= 1) mx = fmaxf(mx, __shfl_xor(mx, off));
    mx = fmaxf(mx, 1e-20f);
    if (lane == 0) swc[o] = mx * (1.0f / 127.0f);
    const float inv = 127.0f / mx;
    short* out = (short*)(wq + (size_t)o * K_DIM);
#pragma unroll
    for (int i = 0; i < 32; ++i) {
      float s = srow[i], z = zrow[i];
      int rlo = (int)rintf(((float)(q[i] & 15) - z) * s * inv);
      int rhi = (int)rintf(((float)((q[i] >> 4) & 15) - z) * s * inv);
      out[i * 64 + lane] = (short)((rlo & 0xff) | (rhi << 8));
    }
  }
}

// ---------- 256x256 i8 GEMM, R9 schedule, BK=128 (R18-verified, unchanged) ----------
__device__ __forceinline__ void gload_lds16(const void* g, void* l) {
  __builtin_amdgcn_global_load_lds((__attribute__((address_space(1))) void*)g,
                                   (__attribute__((address_space(3))) void*)l,
                                   16, 0, 0);
}

// Stage one k-half panel [256 rows][64 i8] (16KB), 2 gload_lds per thread.
__device__ __forceinline__ void stage2(const int8_t* s0, const int8_t* s1,
                                       int8_t* panel, int wave, int koff) {
  gload_lds16(s0 + koff, panel + wave * 1024);
  gload_lds16(s1 + koff, panel + 8192 + wave * 1024);
}

#define VMC(N) asm volatile("s_waitcnt vmcnt(" #N ")" ::: "memory")
#define PUB(N) { VMC(N); __builtin_amdgcn_s_barrier(); }

// Fragment reads (i8: 16B = 16 elems along K per lane).
#define RD_AV(DST, P, MH)                                                    \
  _Pragma("unroll") for (int m_ = 0; m_ < 4; ++m_)                           \
    DST[m_] = *(const i32x4*)((P) + abase + ((MH)*4 + m_) * 1024);
#define RD_BV(DST, P)                                                        \
  _Pragma("unroll") for (int n_ = 0; n_ < 4; ++n_)                           \
    DST[n_] = *(const i32x4*)((P) + bbase + n_ * 1024);

#define MFMA_BLK(MH, AV, BV)                                                 \
  {                                                                          \
    __builtin_amdgcn_s_setprio(1);                                           \
    _Pragma("unroll") for (int m_ = 0; m_ < 4; ++m_)                         \
      _Pragma("unroll") for (int n_ = 0; n_ < 4; ++n_)                       \
        acc[(MH)*4 + m_][n_] = __builtin_amdgcn_mfma_i32_16x16x64_i8(        \
            AV[m_], BV[n_], acc[(MH)*4 + m_][n_], 0, 0, 0);                  \
    __builtin_amdgcn_s_setprio(0);                                           \
  }

__global__ __launch_bounds__(512, 2) void gemm_i8_kernel(const int8_t* __restrict__ A,
                                                         const int8_t* __restrict__ B,
                                                         const float* __restrict__ sx,
                                                         const float* __restrict__ swc,
                                                         float* __restrict__ C) {
  extern __shared__ int8_t lds[];
  int8_t* As = lds;            // [2 buf][2 kh][256*64]  = 64KB
  int8_t* Bs = lds + 65536;    // same                   = 64KB

  const int tid  = threadIdx.x;
  const int wave = tid >> 6;
  const int lane = tid & 63;
  const int wm = wave >> 2;   // 0..1 -> 128-row slab
  const int wn = wave & 3;    // 0..3 -> 64-col slab
  const int fr = lane & 15;
  const int cp = (lane >> 4) ^ ((fr >> 1) & 3);  // swizzled physical 16B-block

  // XCD-chunked block swizzle (1376 = 8*172, bijective), bm-major mapping
  const int wg  = blockIdx.x;
  const int sz_ = (wg & 7) * 172 + (wg >> 3);
  const int bm = sz_ / 43;
  const int bn = sz_ % 43;
  const size_t row0 = (size_t)bm * BM;
  const size_t col0 = (size_t)bn * BN;

  const int8_t* Ab = A + row0 * K_DIM;
  const int8_t* Bb = B + col0 * K_DIM;

  // per-lane staging sources (swizzle baked into global col, rule #21)
  const int cl = (tid & 3) ^ ((tid >> 3) & 3);
  const int r0 = tid >> 2;
  const int8_t* asrc0 = Ab + (size_t)r0 * K_DIM + cl * 16;
  const int8_t* asrc1 = Ab + (size_t)(r0 + 128) * K_DIM + cl * 16;
  const int8_t* bsrc0 = Bb + (size_t)r0 * K_DIM + cl * 16;
  const int8_t* bsrc1 = Bb + (size_t)(r0 + 128) * K_DIM + cl * 16;

  // fragment LDS byte offsets (panel-local); frag mf at abase + mf*1024
  const int abase = (wm * 128 + fr) * 64 + cp * 16;
  const int bbase = (wn * 64 + fr) * 64 + cp * 16;

  i32x4 acc[8][4];
#pragma unroll
  for (int i = 0; i < 8; ++i)
#pragma unroll
    for (int j = 0; j < 4; ++j) acc[i][j] = (i32x4){0, 0, 0, 0};

  i32x4 av0[4], av1[4], bv0[4], bv1[4];

  // ---- prologue: stage tile 0 fully; pre-read P1's fragments ----
  stage2(asrc0, asrc1, As + 0 * 16384, wave, 0);
  stage2(bsrc0, bsrc1, Bs + 0 * 16384, wave, 0);
  stage2(asrc0, asrc1, As + 1 * 16384, wave, 64);
  stage2(bsrc0, bsrc1, Bs + 1 * 16384, wave, 64);
  VMC(4);                       // A0,B0 landed; A1,B1 may be in flight
  __builtin_amdgcn_s_barrier();
  RD_AV(av0, As + 0 * 16384, 0);
  RD_BV(bv0, Bs + 0 * 16384);

  // ---- main loop: R9 schedule, 4 phases/K-tile, publishes at P1/P3 ----
  for (int T = 0; T < NT - 1; ++T) {
    const int buf = T & 1, nb = buf ^ 1;
    int8_t* A0 = As + (buf * 2 + 0) * 16384;
    int8_t* A1 = As + (buf * 2 + 1) * 16384;
    int8_t* B1 = Bs + (buf * 2 + 1) * 16384;
    int8_t* nA0 = As + (nb * 2 + 0) * 16384;
    int8_t* nA1 = As + (nb * 2 + 1) * 16384;
    int8_t* nB0 = Bs + (nb * 2 + 0) * 16384;
    int8_t* nB1 = Bs + (nb * 2 + 1) * 16384;
    const int k0 = (T + 1) * 128;     // prefetch col offset (i8 elems)

    // P1: MFMA(kh0,mh0); pre-read av1<-A0.mh1; stage nA0; PUBLISH kh1
    RD_AV(av1, A0, 1);
    stage2(asrc0, asrc1, nA0, wave, k0);
    MFMA_BLK(0, av0, bv0);
    PUB(2);
    // P2: MFMA(kh0,mh1); pre-read av0<-A1.mh0, bv1<-B1; stage nB0
    RD_AV(av0, A1, 0);
    RD_BV(bv1, B1);
    stage2(bsrc0, bsrc1, nB0, wave, k0);
    MFMA_BLK(1, av1, bv0);
    // P3: MFMA(kh1,mh0); pre-read av1<-A1.mh1; stage nA1; PUBLISH next kh0
    RD_AV(av1, A1, 1);
    stage2(asrc0, asrc1, nA1, wave, k0 + 64);
    MFMA_BLK(0, av0, bv1);
    PUB(2);
    // P4: MFMA(kh1,mh1); pre-read next P1 frags from nA0,nB0; stage nB1
    RD_AV(av0, nA0, 0);
    RD_BV(bv0, nB0);
    stage2(bsrc0, bsrc1, nB1, wave, k0 + 64);
    MFMA_BLK(1, av1, bv1);
  }
  // ---- last tile: no staging; drain remaining at P1-end ----
  {
    const int buf = (NT - 1) & 1;
    int8_t* A0 = As + (buf * 2 + 0) * 16384;
    int8_t* A1 = As + (buf * 2 + 1) * 16384;
    int8_t* B1 = Bs + (buf * 2 + 1) * 16384;
    RD_AV(av1, A0, 1);
    MFMA_BLK(0, av0, bv0);
    PUB(0);                      // retires nA1,nB1 -> A1,B1 readable
    RD_AV(av0, A1, 0);
    RD_BV(bv1, B1);
    MFMA_BLK(1, av1, bv0);
    RD_AV(av1, A1, 1);
    MFMA_BLK(0, av0, bv1);
    MFMA_BLK(1, av1, bv1);
  }

  // ---- epilogue: out = sx[row] * swc[col] * (f32)acc ----
  const int orow = (lane >> 4) * 4;
#pragma unroll
  for (int mi = 0; mi < 8; ++mi) {
    const size_t r = row0 + wm * 128 + mi * 16 + orow;
    const f32x4 sx4 = *(const f32x4*)(sx + r);
#pragma unroll
    for (int n = 0; n < 4; ++n) {
      const size_t c = col0 + wn * 64 + n * 16 + fr;
      const float sw = swc[c];
#pragma unroll
      for (int v = 0; v < 4; ++v)
        C[(r + v) * N_DIM + c] = (float)acc[mi][n][v] * sx4[v] * sw;
    }
  }
}

// ---------- fallback (only if d_ws too small): naive fused ----------
__global__ __launch_bounds__(256) void fallback_kernel(const float* __restrict__ x,
                                                       const int* __restrict__ qw,
                                                       const float* __restrict__ sc,
                                                       const float* __restrict__ zp,
                                                       float* __restrict__ out) {
  __shared__ float xs[K_DIM];
  const int m = blockIdx.y;
  const int n = blockIdx.x * 256 + threadIdx.x;
  for (int i = threadIdx.x; i < K_DIM; i += 256) xs[i] = x[(size_t)m * K_DIM + i];
  __syncthreads();
  float acc = 0.f;
  const int* wrow = qw + (size_t)n * (K_DIM / 2);
  for (int g = 0; g < NGROUP; ++g) {
    float s = sc[n * NGROUP + g];
    float z = zp[n * NGROUP + g];
    float partial = 0.f;
    for (int p = 0; p < 64; ++p) {
      int q = wrow[g * 64 + p];
      partial += xs[g * 128 + 2 * p]     * ((float)(q & 15) - z);
      partial += xs[g * 128 + 2 * p + 1] * ((float)((q >> 4) & 15) - z);
    }
    acc = fmaf(partial, s, acc);
  }
  out[(size_t)m * N_DIM + n] = acc;
}

extern "C" void kernel_launch(void* const* d_in, const int* in_sizes, int n_in,
                              void* d_out, int out_size, void* d_ws, size_t ws_size,
                              hipStream_t stream) {
  const float* x  = (const float*)d_in[0];
  const int*   qw = (const int*)d_in[1];
  const float* sc = (const float*)d_in[2];
  const float* zp = (const float*)d_in[3];
  float* out = (float*)d_out;

  const size_t xq_bytes = (size_t)M_DIM * K_DIM;        // 33,554,432
  const size_t wq_bytes = (size_t)N_DIM * K_DIM;        // 45,088,768
  const size_t sx_bytes = (size_t)M_DIM * 4;
  const size_t sw_bytes = (size_t)N_DIM * 4;

  if (ws_size >= xq_bytes + wq_bytes + sx_bytes + sw_bytes) {
    int8_t* xq = (int8_t*)d_ws;
    int8_t* wq = (int8_t*)d_ws + xq_bytes;
    float* sx  = (float*)((char*)d_ws + xq_bytes + wq_bytes);
    float* swc = (float*)((char*)d_ws + xq_bytes + wq_bytes + sx_bytes);
    // fused prepass: x-rows (8192 blocks) + W-rows (2752 blocks) overlap on the GPU
    quant_fused_kernel<<<dim3(M_DIM + N_DIM / 4), 256, 0, stream>>>(
        x, xq, sx, qw, sc, zp, wq, swc);
    dim3 grid((M_DIM / BM) * (N_DIM / BN));  // 32*43 = 1376
    gemm_i8_kernel<<<grid, dim3(512), 131072, stream>>>(xq, wq, sx, swc, out);
  } else {
    dim3 grid(N_DIM / 256, M_DIM);
    fallback_kernel<<<grid, 256, 0, stream>>>(x, qw, sc, zp, out);
  }
}

// Round 20
// 424.751 us; speedup vs baseline: 1.8089x; 1.0450x over previous
//
#include <hip/hip_runtime.h>
#include <hip/hip_bf16.h>
#include <stdint.h>

// Problem constants: B=4, S=2048, IN=4096, OUT=11008
#define M_DIM 8192   // B*S
#define N_DIM 11008  // OUT
#define K_DIM 4096   // IN
#define NGROUP 32    // K_DIM/128

#define BM 256
#define BN 256
#define BK 128
#define NT (K_DIM / BK)  // 32 K-tiles

typedef __attribute__((ext_vector_type(4))) int i32x4;
typedef __attribute__((ext_vector_type(4))) float f32x4;

static_assert(M_DIM % BM == 0 && N_DIM % BN == 0 && K_DIM % BK == 0, "tiling");

// ---------- fused prepass: blocks [0,8192) quantize x rows; [8192,10944) quantize W rows ----------
__global__ __launch_bounds__(256) void quant_fused_kernel(const float* __restrict__ x,
                                                          int8_t* __restrict__ xq,
                                                          float* __restrict__ sx,
                                                          const int* __restrict__ qw,
                                                          const float* __restrict__ sc,
                                                          const float* __restrict__ zp,
                                                          int8_t* __restrict__ wq,
                                                          float* __restrict__ swc) {
  __shared__ float red[4];
  __shared__ float sfin;
  const int tid = threadIdx.x;

  if (blockIdx.x < M_DIM) {
    // ---- x row -> i8, per-row scale ----
    const int m = blockIdx.x;
    const float* xr = x + (size_t)m * K_DIM;
    float4 v[4];
    float mx = 0.f;
#pragma unroll
    for (int i = 0; i < 4; ++i) {
      v[i] = *(const float4*)(xr + tid * 16 + i * 4);
      mx = fmaxf(mx, fmaxf(fmaxf(fabsf(v[i].x), fabsf(v[i].y)),
                           fmaxf(fabsf(v[i].z), fabsf(v[i].w))));
    }
#pragma unroll
    for (int off = 32; off; off >>= 1) mx = fmaxf(mx, __shfl_xor(mx, off));
    if ((tid & 63) == 0) red[tid >> 6] = mx;
    __syncthreads();
    if (tid == 0) {
      float t = fmaxf(fmaxf(red[0], red[1]), fmaxf(red[2], red[3]));
      t = fmaxf(t, 1e-20f);
      sfin = t;
      sx[m] = t * (1.0f / 127.0f);
    }
    __syncthreads();
    const float inv = 127.0f / sfin;
    int o[4];
#pragma unroll
    for (int i = 0; i < 4; ++i) {
      int q0 = (int)rintf(v[i].x * inv), q1 = (int)rintf(v[i].y * inv);
      int q2 = (int)rintf(v[i].z * inv), q3 = (int)rintf(v[i].w * inv);
      o[i] = (q0 & 0xff) | ((q1 & 0xff) << 8) | ((q2 & 0xff) << 16) | (q3 << 24);
    }
    *(int4*)(xq + (size_t)m * K_DIM + tid * 16) = make_int4(o[0], o[1], o[2], o[3]);
  } else {
    // ---- W row -> i8, per-output-row scale; single global read (row held in regs) ----
    const int o = (blockIdx.x - M_DIM) * 4 + (tid >> 6);
    const int lane = tid & 63;
    const int* row = qw + (size_t)o * 2048;
    const float* srow = sc + o * NGROUP;
    const float* zrow = zp + o * NGROUP;
    int q[32];
    float mx = 0.f;
#pragma unroll
    for (int i = 0; i < 32; ++i) {
      q[i] = row[i * 64 + lane];
      float s = srow[i], z = zrow[i];
      float lo = ((float)(q[i] & 15) - z) * s;
      float hi = ((float)((q[i] >> 4) & 15) - z) * s;
      mx = fmaxf(mx, fmaxf(fabsf(lo), fabsf(hi)));
    }
#pragma unroll
    for (int off = 32; off; off >>= 1) mx = fmaxf(mx, __shfl_xor(mx, off));
    mx = fmaxf(mx, 1e-20f);
    if (lane == 0) swc[o] = mx * (1.0f / 127.0f);
    const float inv = 127.0f / mx;
    short* out = (short*)(wq + (size_t)o * K_DIM);
#pragma unroll
    for (int i = 0; i < 32; ++i) {
      float s = srow[i], z = zrow[i];
      int rlo = (int)rintf(((float)(q[i] & 15) - z) * s * inv);
      int rhi = (int)rintf(((float)((q[i] >> 4) & 15) - z) * s * inv);
      out[i * 64 + lane] = (short)((rlo & 0xff) | (rhi << 8));
    }
  }
}

// ---------- 256x256 i8 GEMM, R9 schedule, BK=128 (R18-verified schedule) ----------
__device__ __forceinline__ void gload_lds16(const void* g, void* l) {
  __builtin_amdgcn_global_load_lds((__attribute__((address_space(1))) void*)g,
                                   (__attribute__((address_space(3))) void*)l,
                                   16, 0, 0);
}

// Stage one k-half panel [256 rows][64 i8] (16KB), 2 gload_lds per thread.
__device__ __forceinline__ void stage2(const int8_t* s0, const int8_t* s1,
                                       int8_t* panel, int wave, int koff) {
  gload_lds16(s0 + koff, panel + wave * 1024);
  gload_lds16(s1 + koff, panel + 8192 + wave * 1024);
}

#define VMC(N) asm volatile("s_waitcnt vmcnt(" #N ")" ::: "memory")
#define PUB(N) { VMC(N); __builtin_amdgcn_s_barrier(); }

// Fragment reads (i8: 16B = 16 elems along K per lane).
#define RD_AV(DST, P, MH)                                                    \
  _Pragma("unroll") for (int m_ = 0; m_ < 4; ++m_)                           \
    DST[m_] = *(const i32x4*)((P) + abase + ((MH)*4 + m_) * 1024);
#define RD_BV(DST, P)                                                        \
  _Pragma("unroll") for (int n_ = 0; n_ < 4; ++n_)                           \
    DST[n_] = *(const i32x4*)((P) + bbase + n_ * 1024);

#define MFMA_BLK(MH, AV, BV)                                                 \
  {                                                                          \
    __builtin_amdgcn_s_setprio(1);                                           \
    _Pragma("unroll") for (int m_ = 0; m_ < 4; ++m_)                         \
      _Pragma("unroll") for (int n_ = 0; n_ < 4; ++n_)                       \
        acc[(MH)*4 + m_][n_] = __builtin_amdgcn_mfma_i32_16x16x64_i8(        \
            AV[m_], BV[n_], acc[(MH)*4 + m_][n_], 0, 0, 0);                  \
    __builtin_amdgcn_s_setprio(0);                                           \
  }

__global__ __launch_bounds__(512, 2) void gemm_i8_kernel(const int8_t* __restrict__ A,
                                                         const int8_t* __restrict__ B,
                                                         const float* __restrict__ sx,
                                                         const float* __restrict__ swc,
                                                         float* __restrict__ C) {
  extern __shared__ int8_t lds[];
  int8_t* As = lds;            // [2 buf][2 kh][256*64]  = 64KB
  int8_t* Bs = lds + 65536;    // same                   = 64KB

  const int tid  = threadIdx.x;
  const int wave = tid >> 6;
  const int lane = tid & 63;
  const int wm = wave >> 2;   // 0..1 -> 128-row slab
  const int wn = wave & 3;    // 0..3 -> 64-col slab
  const int fr = lane & 15;
  const int cp = (lane >> 4) ^ ((fr >> 1) & 3);  // swizzled physical 16B-block

  // 2D XCD supertile (bijective): xcd = wg&7 gets 4 bm x 43 bn, bm fastest.
  // Concurrent blocks on an XCD share 4 A-panels (4MB, L2-resident) and
  // 4-way-share B-panels, instead of streaming 32 distinct B-panels.
  const int wg  = blockIdx.x;
  const int xcd = wg & 7;
  const int j   = wg >> 3;          // 0..171
  const int bm  = xcd * 4 + (j & 3);
  const int bn  = j >> 2;           // 0..42
  const size_t row0 = (size_t)bm * BM;
  const size_t col0 = (size_t)bn * BN;

  const int8_t* Ab = A + row0 * K_DIM;
  const int8_t* Bb = B + col0 * K_DIM;

  // per-lane staging sources (swizzle baked into global col, rule #21)
  const int cl = (tid & 3) ^ ((tid >> 3) & 3);
  const int r0 = tid >> 2;
  const int8_t* asrc0 = Ab + (size_t)r0 * K_DIM + cl * 16;
  const int8_t* asrc1 = Ab + (size_t)(r0 + 128) * K_DIM + cl * 16;
  const int8_t* bsrc0 = Bb + (size_t)r0 * K_DIM + cl * 16;
  const int8_t* bsrc1 = Bb + (size_t)(r0 + 128) * K_DIM + cl * 16;

  // fragment LDS byte offsets (panel-local); frag mf at abase + mf*1024
  const int abase = (wm * 128 + fr) * 64 + cp * 16;
  const int bbase = (wn * 64 + fr) * 64 + cp * 16;

  i32x4 acc[8][4];
#pragma unroll
  for (int i = 0; i < 8; ++i)
#pragma unroll
    for (int j2 = 0; j2 < 4; ++j2) acc[i][j2] = (i32x4){0, 0, 0, 0};

  i32x4 av0[4], av1[4], bv0[4], bv1[4];

  // ---- prologue: stage tile 0 fully; pre-read P1's fragments ----
  stage2(asrc0, asrc1, As + 0 * 16384, wave, 0);
  stage2(bsrc0, bsrc1, Bs + 0 * 16384, wave, 0);
  stage2(asrc0, asrc1, As + 1 * 16384, wave, 64);
  stage2(bsrc0, bsrc1, Bs + 1 * 16384, wave, 64);
  VMC(4);                       // A0,B0 landed; A1,B1 may be in flight
  __builtin_amdgcn_s_barrier();
  RD_AV(av0, As + 0 * 16384, 0);
  RD_BV(bv0, Bs + 0 * 16384);

  // ---- main loop: R9 schedule, 4 phases/K-tile, publishes at P1/P3 ----
  for (int T = 0; T < NT - 1; ++T) {
    const int buf = T & 1, nb = buf ^ 1;
    int8_t* A0 = As + (buf * 2 + 0) * 16384;
    int8_t* A1 = As + (buf * 2 + 1) * 16384;
    int8_t* B1 = Bs + (buf * 2 + 1) * 16384;
    int8_t* nA0 = As + (nb * 2 + 0) * 16384;
    int8_t* nA1 = As + (nb * 2 + 1) * 16384;
    int8_t* nB0 = Bs + (nb * 2 + 0) * 16384;
    int8_t* nB1 = Bs + (nb * 2 + 1) * 16384;
    const int k0 = (T + 1) * 128;     // prefetch col offset (i8 elems)

    // P1: MFMA(kh0,mh0); pre-read av1<-A0.mh1; stage nA0; PUBLISH kh1
    RD_AV(av1, A0, 1);
    stage2(asrc0, asrc1, nA0, wave, k0);
    MFMA_BLK(0, av0, bv0);
    PUB(2);
    // P2: MFMA(kh0,mh1); pre-read av0<-A1.mh0, bv1<-B1; stage nB0
    RD_AV(av0, A1, 0);
    RD_BV(bv1, B1);
    stage2(bsrc0, bsrc1, nB0, wave, k0);
    MFMA_BLK(1, av1, bv0);
    // P3: MFMA(kh1,mh0); pre-read av1<-A1.mh1; stage nA1; PUBLISH next kh0
    RD_AV(av1, A1, 1);
    stage2(asrc0, asrc1, nA1, wave, k0 + 64);
    MFMA_BLK(0, av0, bv1);
    PUB(2);
    // P4: MFMA(kh1,mh1); pre-read next P1 frags from nA0,nB0; stage nB1
    RD_AV(av0, nA0, 0);
    RD_BV(bv0, nB0);
    stage2(bsrc0, bsrc1, nB1, wave, k0 + 64);
    MFMA_BLK(1, av1, bv1);
  }
  // ---- last tile: no staging; drain remaining at P1-end ----
  {
    const int buf = (NT - 1) & 1;
    int8_t* A0 = As + (buf * 2 + 0) * 16384;
    int8_t* A1 = As + (buf * 2 + 1) * 16384;
    int8_t* B1 = Bs + (buf * 2 + 1) * 16384;
    RD_AV(av1, A0, 1);
    MFMA_BLK(0, av0, bv0);
    PUB(0);                      // retires nA1,nB1 -> A1,B1 readable
    RD_AV(av0, A1, 0);
    RD_BV(bv1, B1);
    MFMA_BLK(1, av1, bv0);
    RD_AV(av1, A1, 1);
    MFMA_BLK(0, av0, bv1);
    MFMA_BLK(1, av1, bv1);
  }

  // ---- epilogue: out = sx[row] * swc[col] * (f32)acc; nontemporal stores
  //      (360MB C stream bypasses L2/L3 so it doesn't evict A/B panels) ----
  const int orow = (lane >> 4) * 4;
#pragma unroll
  for (int mi = 0; mi < 8; ++mi) {
    const size_t r = row0 + wm * 128 + mi * 16 + orow;
    const f32x4 sx4 = *(const f32x4*)(sx + r);
#pragma unroll
    for (int n = 0; n < 4; ++n) {
      const size_t c = col0 + wn * 64 + n * 16 + fr;
      const float sw = swc[c];
#pragma unroll
      for (int v = 0; v < 4; ++v)
        __builtin_nontemporal_store((float)acc[mi][n][v] * sx4[v] * sw,
                                    &C[(r + v) * N_DIM + c]);
    }
  }
}

// ---------- fallback (only if d_ws too small): naive fused ----------
__global__ __launch_bounds__(256) void fallback_kernel(const float* __restrict__ x,
                                                       const int* __restrict__ qw,
                                                       const float* __restrict__ sc,
                                                       const float* __restrict__ zp,
                                                       float* __restrict__ out) {
  __shared__ float xs[K_DIM];
  const int m = blockIdx.y;
  const int n = blockIdx.x * 256 + threadIdx.x;
  for (int i = threadIdx.x; i < K_DIM; i += 256) xs[i] = x[(size_t)m * K_DIM + i];
  __syncthreads();
  float acc = 0.f;
  const int* wrow = qw + (size_t)n * (K_DIM / 2);
  for (int g = 0; g < NGROUP; ++g) {
    float s = sc[n * NGROUP + g];
    float z = zp[n * NGROUP + g];
    float partial = 0.f;
    for (int p = 0; p < 64; ++p) {
      int q = wrow[g * 64 + p];
      partial += xs[g * 128 + 2 * p]     * ((float)(q & 15) - z);
      partial += xs[g * 128 + 2 * p + 1] * ((float)((q >> 4) & 15) - z);
    }
    acc = fmaf(partial, s, acc);
  }
  out[(size_t)m * N_DIM + n] = acc;
}

extern "C" void kernel_launch(void* const* d_in, const int* in_sizes, int n_in,
                              void* d_out, int out_size, void* d_ws, size_t ws_size,
                              hipStream_t stream) {
  const float* x  = (const float*)d_in[0];
  const int*   qw = (const int*)d_in[1];
  const float* sc = (const float*)d_in[2];
  const float* zp = (const float*)d_in[3];
  float* out = (float*)d_out;

  const size_t xq_bytes = (size_t)M_DIM * K_DIM;        // 33,554,432
  const size_t wq_bytes = (size_t)N_DIM * K_DIM;        // 45,088,768
  const size_t sx_bytes = (size_t)M_DIM * 4;
  const size_t sw_bytes = (size_t)N_DIM * 4;

  if (ws_size >= xq_bytes + wq_bytes + sx_bytes + sw_bytes) {
    int8_t* xq = (int8_t*)d_ws;
    int8_t* wq = (int8_t*)d_ws + xq_bytes;
    float* sx  = (float*)((char*)d_ws + xq_bytes + wq_bytes);
    float* swc = (float*)((char*)d_ws + xq_bytes + wq_bytes + sx_bytes);
    quant_fused_kernel<<<dim3(M_DIM + N_DIM / 4), 256, 0, stream>>>(
        x, xq, sx, qw, sc, zp, wq, swc);
    dim3 grid((M_DIM / BM) * (N_DIM / BN));  // 32*43 = 1376
    gemm_i8_kernel<<<grid, dim3(512), 131072, stream>>>(xq, wq, sx, swc, out);
  } else {
    dim3 grid(N_DIM / 256, M_DIM);
    fallback_kernel<<<grid, 256, 0, stream>>>(x, qw, sc, zp, out);
  }
}